// Round 5
// baseline (807.616 us; speedup 1.0000x reference)
//
#include <hip/hip_runtime.h>

#define NODES 50000
#define FEAT  256
#define RELS  4
#define EDGES 80000
#define NV4   20000          // EDGES / 4

typedef __bf16 bf16x8  __attribute__((ext_vector_type(8)));
typedef float  floatx4 __attribute__((ext_vector_type(4)));

struct BF8U { union { unsigned short u[8]; bf16x8 v; uint4 q; }; };

static __device__ __forceinline__ float bf2f(unsigned short u) {
  union { unsigned u; float f; } v; v.u = (unsigned)u << 16; return v.f;
}
static __device__ __forceinline__ unsigned short f2bf(float f) {
  union { float f; unsigned u; } v; v.f = f;
  unsigned r = v.u + 0x7FFFu + ((v.u >> 16) & 1u);   // RNE
  return (unsigned short)(r >> 16);
}

// 8 consecutive f32 -> bf16x8 A-fragment, scaled
static __device__ __forceinline__ bf16x8 cvt8(const float* p, float s) {
  float4 a = ((const float4*)p)[0], b = ((const float4*)p)[1];
  BF8U r;
  r.u[0] = f2bf(a.x * s); r.u[1] = f2bf(a.y * s);
  r.u[2] = f2bf(a.z * s); r.u[3] = f2bf(a.w * s);
  r.u[4] = f2bf(b.x * s); r.u[5] = f2bf(b.y * s);
  r.u[6] = f2bf(b.z * s); r.u[7] = f2bf(b.w * s);
  return r.v;
}

// Stage rows [kc*32, kc*32+32) of a 256x256 f32 weight chunk into B-fragment
// order: sB frag (nc,lane) j = W[kc*32+(lane>>4)*8+j][nc*16+(lane&15)]
static __device__ __forceinline__ void stage_b(const float* __restrict__ Wc, int kc,
                                               unsigned short* sB, int tid, int nthr) {
  for (int t = tid; t < 1024; t += nthr) {
    int ln = t & 63, nc = t >> 6;
    const float* wp = Wc + (size_t)(kc * 32 + (ln >> 4) * 8) * 256 + nc * 16 + (ln & 15);
    BF8U vv;
#pragma unroll
    for (int j = 0; j < 8; ++j) vv.u[j] = f2bf(wp[(size_t)j * 256]);
    ((uint4*)sB)[t] = vv.q;
  }
}

// ===========================================================================
// Variant A: 128 rows/block, 512 thr (8 waves x 16 rows), f32 LDS agg.
// LDS = 133120 + 16384 + 512 = 150016 B (gfx950 workgroup LDS cap is 160 KiB).
#define AROWS 128
#define ASTR  260   // f32 stride; 260 % 32 == 4 -> conflict-benign b128 reads
#define ABLK  512

__global__ __launch_bounds__(ABLK) void rgcn_big(
    const float* __restrict__ x, const int* __restrict__ src,
    const int* __restrict__ dst, const float* __restrict__ w,
    const float* __restrict__ sw, const float* __restrict__ bias,
    float* __restrict__ out) {
  __shared__ float sAgg[AROWS * ASTR];
  __shared__ unsigned short sB[8192];
  __shared__ unsigned sDeg[AROWS];

  const int tid = threadIdx.x, wave = tid >> 6, lane = tid & 63;
  const int quad = lane >> 4, l15 = lane & 15;
  const int m0 = blockIdx.x * AROWS;
  const int wrow = wave * 16;                     // wave's 16-row window

  floatx4 acc[16] = {};
  const floatx4 fz = {0.f, 0.f, 0.f, 0.f};

  for (int r = 0; r < RELS; ++r) {
    for (int t = tid; t < (AROWS * ASTR) / 4; t += ABLK) ((floatx4*)sAgg)[t] = fz;
    if (tid < AROWS) sDeg[tid] = 0u;
    __syncthreads();

    const int4* sr4 = (const int4*)(src + r * EDGES);
    const int4* dr4 = (const int4*)(dst + r * EDGES);
    for (int i0 = tid; i0 < 20480; i0 += ABLK) {   // 40 iters, all threads
      int4 d4 = {-1, -1, -1, -1}, s4 = {0, 0, 0, 0};
      if (i0 < NV4) { d4 = dr4[i0]; s4 = sr4[i0]; }
      int dd[4] = {d4.x, d4.y, d4.z, d4.w};
      int ss[4] = {s4.x, s4.y, s4.z, s4.w};
#pragma unroll
      for (int j = 0; j < 4; ++j) {
        unsigned u = (unsigned)(dd[j] - m0);
        unsigned long long mb = __ballot(u < (unsigned)AROWS);
        while (mb) {
          int jl = (int)__ffsll(mb) - 1; mb &= mb - 1;
          int s  = __shfl(ss[j], jl);
          int ul = __shfl((int)u, jl);
          if (lane == 0) atomicAdd(&sDeg[ul], 1u);
          const float* xp = x + (size_t)s * FEAT + lane;
          float* ap = sAgg + ul * ASTR + lane;
#pragma unroll
          for (int k = 0; k < 4; ++k) atomicAdd(ap + k * 64, xp[k * 64]);
        }
      }
    }
    __syncthreads();

    unsigned dg = sDeg[wrow + l15];
    float rs = 1.0f / (float)(dg ? dg : 1u);

    const float* Wc = w + (size_t)r * 65536;
    for (int kc = 0; kc < 8; ++kc) {
      stage_b(Wc, kc, sB, tid, ABLK);
      __syncthreads();
      bf16x8 a = cvt8(&sAgg[(wrow + l15) * ASTR + kc * 32 + quad * 8], rs);
#pragma unroll
      for (int ns = 0; ns < 16; ++ns) {
        BF8U b8; b8.q = ((const uint4*)sB)[ns * 64 + lane];
        acc[ns] = __builtin_amdgcn_mfma_f32_16x16x32_bf16(a, b8.v, acc[ns], 0, 0, 0);
      }
      __syncthreads();
    }
  }

  // self-loop chunk: A = x rows directly
  {
    int row = m0 + wrow + l15;
    if (row >= NODES) row = NODES - 1;            // dup compute; stores guarded
    for (int kc = 0; kc < 8; ++kc) {
      stage_b(sw, kc, sB, tid, ABLK);
      __syncthreads();
      bf16x8 a = cvt8(x + (size_t)row * FEAT + kc * 32 + quad * 8, 1.0f);
#pragma unroll
      for (int ns = 0; ns < 16; ++ns) {
        BF8U b8; b8.q = ((const uint4*)sB)[ns * 64 + lane];
        acc[ns] = __builtin_amdgcn_mfma_f32_16x16x32_bf16(a, b8.v, acc[ns], 0, 0, 0);
      }
      __syncthreads();
    }
  }

  // epilogue: C/D layout row = quad*4 + reg, col = lane&15  (f32 stores!)
#pragma unroll
  for (int i = 0; i < 4; ++i) {
    int row = m0 + wrow + quad * 4 + i;
    if (row < NODES) {
      float* op = out + (size_t)row * FEAT;
#pragma unroll
      for (int ns = 0; ns < 16; ++ns) {
        int col = ns * 16 + l15;
        op[col] = fmaxf(acc[ns][i] + bias[col], 0.0f);
      }
    }
  }
}

// ===========================================================================
// Variant B (fallback if 150 KB LDS won't launch): 64 rows/block, 256 thr,
// wave-private bf16 LDS agg (race-free RMW), 50.4 KB LDS.
#define BROWS 64
#define BSTR  264
#define BBLK  256

__global__ __launch_bounds__(BBLK) void rgcn_small(
    const float* __restrict__ x, const int* __restrict__ src,
    const int* __restrict__ dst, const float* __restrict__ w,
    const float* __restrict__ sw, const float* __restrict__ bias,
    float* __restrict__ out) {
  __shared__ unsigned short sAgg[BROWS * BSTR];
  __shared__ unsigned short sB[8192];
  __shared__ unsigned sDeg[BROWS];

  const int tid = threadIdx.x, wave = tid >> 6, lane = tid & 63;
  const int quad = lane >> 4, l15 = lane & 15;
  const int m0 = blockIdx.x * BROWS;
  const int w0 = m0 + wave * 16;

  floatx4 acc[16] = {};
  const uint4 uz = {0u, 0u, 0u, 0u};

  for (int r = 0; r < RELS; ++r) {
    for (int t = tid; t < (BROWS * BSTR) / 8; t += BBLK) ((uint4*)sAgg)[t] = uz;
    if (tid < BROWS) sDeg[tid] = 0u;
    __syncthreads();

    const int4* sr4 = (const int4*)(src + r * EDGES);
    const int4* dr4 = (const int4*)(dst + r * EDGES);
    for (int i0 = lane; i0 < 20032; i0 += 64) {    // each wave scans all edges
      int4 d4 = {-1, -1, -1, -1}, s4 = {0, 0, 0, 0};
      if (i0 < NV4) { d4 = dr4[i0]; s4 = sr4[i0]; }
      int dd[4] = {d4.x, d4.y, d4.z, d4.w};
      int ss[4] = {s4.x, s4.y, s4.z, s4.w};
#pragma unroll
      for (int j = 0; j < 4; ++j) {
        unsigned u = (unsigned)(dd[j] - w0);
        unsigned long long mb = __ballot(u < 16u);
        while (mb) {
          int jl = (int)__ffsll(mb) - 1; mb &= mb - 1;
          int s  = __shfl(ss[j], jl);
          int ur = wave * 16 + __shfl((int)u, jl);
          if (lane == 0) sDeg[ur] += 1u;
          const float* xp = x + (size_t)s * FEAT + lane;
          unsigned short* ap = sAgg + ur * BSTR + lane;
#pragma unroll
          for (int k = 0; k < 4; ++k)
            ap[k * 64] = f2bf(bf2f(ap[k * 64]) + xp[k * 64]);
        }
      }
    }
    __syncthreads();
    for (int rr = 0; rr < 16; ++rr) {              // wave-local 1/deg scaling
      unsigned dg = sDeg[wave * 16 + rr];
      if (dg > 1u) {
        float sc = 1.0f / (float)dg;
        unsigned short* ap = sAgg + (wave * 16 + rr) * BSTR + lane;
#pragma unroll
        for (int k = 0; k < 4; ++k) ap[k * 64] = f2bf(bf2f(ap[k * 64]) * sc);
      }
    }
    __syncthreads();

    const float* Wc = w + (size_t)r * 65536;
    for (int kc = 0; kc < 8; ++kc) {
      stage_b(Wc, kc, sB, tid, BBLK);
      __syncthreads();
      BF8U t8;
      t8.q = *(const uint4*)(sAgg + (wave * 16 + l15) * BSTR + kc * 32 + quad * 8);
#pragma unroll
      for (int ns = 0; ns < 16; ++ns) {
        BF8U b8; b8.q = ((const uint4*)sB)[ns * 64 + lane];
        acc[ns] = __builtin_amdgcn_mfma_f32_16x16x32_bf16(t8.v, b8.v, acc[ns], 0, 0, 0);
      }
      __syncthreads();
    }
  }

  {
    int row = w0 + l15;
    if (row >= NODES) row = NODES - 1;
    for (int kc = 0; kc < 8; ++kc) {               // self-loop chunk
      stage_b(sw, kc, sB, tid, BBLK);
      __syncthreads();
      bf16x8 a = cvt8(x + (size_t)row * FEAT + kc * 32 + quad * 8, 1.0f);
#pragma unroll
      for (int ns = 0; ns < 16; ++ns) {
        BF8U b8; b8.q = ((const uint4*)sB)[ns * 64 + lane];
        acc[ns] = __builtin_amdgcn_mfma_f32_16x16x32_bf16(a, b8.v, acc[ns], 0, 0, 0);
      }
      __syncthreads();
    }
  }

#pragma unroll
  for (int i = 0; i < 4; ++i) {
    int row = w0 + quad * 4 + i;
    if (row < NODES) {
      float* op = out + (size_t)row * FEAT;
#pragma unroll
      for (int ns = 0; ns < 16; ++ns) {
        int col = ns * 16 + l15;
        op[col] = fmaxf(acc[ns][i] + bias[col], 0.0f);
      }
    }
  }
}

// ===========================================================================
extern "C" void kernel_launch(void* const* d_in, const int* in_sizes, int n_in,
                              void* d_out, int out_size, void* d_ws, size_t ws_size,
                              hipStream_t stream) {
  const float* x    = (const float*)d_in[0];   // [50000,256] f32
  const int*   src  = (const int*)d_in[1];     // [4,80000]
  const int*   dst  = (const int*)d_in[2];     // [4,80000]
  const float* w    = (const float*)d_in[3];   // [4,256,256] f32
  const float* sw   = (const float*)d_in[4];   // [256,256] f32
  const float* bias = (const float*)d_in[5];   // [256] f32
  float*       out  = (float*)d_out;           // [50000,256] f32
  (void)d_ws; (void)ws_size; (void)in_sizes; (void)n_in; (void)out_size;

  int maxlds = 0;
  hipDeviceGetAttribute(&maxlds, hipDeviceAttributeMaxSharedMemoryPerBlock, 0);

  if (maxlds >= 150016) {
    rgcn_big<<<(NODES + AROWS - 1) / AROWS, ABLK, 0, stream>>>(
        x, src, dst, w, sw, bias, out);
  } else {
    rgcn_small<<<(NODES + BROWS - 1) / BROWS, BBLK, 0, stream>>>(
        x, src, dst, w, sw, bias, out);
  }
}